// Round 21
// baseline (219.320 us; speedup 1.0000x reference)
//
#include <hip/hip_runtime.h>

typedef short bf16x8 __attribute__((ext_vector_type(8)));
typedef float f32x4 __attribute__((ext_vector_type(4)));
typedef unsigned int u32x2 __attribute__((ext_vector_type(2)));
typedef unsigned int u32x4 __attribute__((ext_vector_type(4)));

__device__ __forceinline__ unsigned short f2b(float f) {
    unsigned int u = __builtin_bit_cast(unsigned int, f);
    u += 0x7fffu + ((u >> 16) & 1u);   // RNE
    return (unsigned short)(u >> 16);
}
__device__ __forceinline__ float hi2f(unsigned int u) {
    return __builtin_bit_cast(float, u & 0xffff0000u);
}
__device__ __forceinline__ float lo2f(unsigned int u) {
    return __builtin_bit_cast(float, u << 16);
}

// wt[k][i][j] = bf16(w1[j][k][i]);  k<3, i<128, j<64
__global__ void wt_prepass(const float* __restrict__ w1, unsigned short* __restrict__ wt) {
    int t = blockIdx.x * 256 + threadIdx.x;
    if (t >= 24576) return;
    int j = t & 63;
    int i = (t >> 6) & 127;
    int k = t >> 13;
    wt[t] = f2b(w1[(j * 3 + k) * 128 + i]);
}

// xs: row = a*13 + s; byte = (row<<7) + ((j*2) ^ ((row&7)<<4))   [46592 B]
// t4s (overlay): [ic][l][cl] u16, byte = ic*464 + l*16 + cl*2   [59392 B]
// epilogue: C-quad = 4 consecutive cl at fixed l -> plain-C++ pack + 1 ds_write_b64
//   (r20's inline-asm cvt_pk on MFMA acc inputs produced NaN; plain packs instead)
// combine: task (iloc, lq) reads 4 x b128 (full cl rows, 4 l's), computes all 7 m.

__global__ __launch_bounds__(512, 4) void fused_main(
        const float* __restrict__ x, const float* __restrict__ w0,
        const unsigned short* __restrict__ wt, float* __restrict__ y) {
    __shared__ __align__(16) char smem[65536];   // xs (46.6K) then t4s (59.4K)
    __shared__ float w0s[256];

    const int tid  = threadIdx.x;
    const int lane = tid & 63;
    const int w    = tid >> 6;          // 0..7
    const int rl   = lane & 15;
    const int jb0  = (lane >> 4) << 3;

    // same-XCD sibling mapping (bc-siblings of one b are 8 dispatch-slots apart)
    const int B   = (int)blockIdx.x;
    const int b   = ((B & 7) << 7) + ((B >> 3) >> 2);
    const int bc  = (B >> 3) & 3;
    const int c0  = 7 * bc;

    if (tid < 256) w0s[tid] = w0[tid];

    // ---- zero-fill halo slots (bc0: s=0,11 ; bc3: s=9) ----
    {
        int nh = (bc == 0) ? 2 : ((bc == 3) ? 1 : 0);
        for (int idx = tid; idx < nh * 224; idx += 512) {
            int rr = idx;
            int sl;
            if (bc == 0) {
                if (rr >= 224) { sl = 11; rr -= 224; } else sl = 0;
            } else {
                sl = 9;                 // bc == 3
            }
            int a   = rr >> 3, ch = rr & 7;
            int row = a * 13 + sl;
            int byte = (row << 7) + ((ch << 4) ^ ((row & 7) << 4));
            *reinterpret_cast<f32x4*>(smem + byte) = f32x4{0.f, 0.f, 0.f, 0.f};
        }
    }

    // ---- staging: pair-units (rows 2jp and 2jp+1), b32 packed scatter (r19, validated) ----
    int q0, q1, q2;
    if      (bc == 0) { q0 = 0; q1 = 1; q2 = 6; }
    else if (bc == 1) { q0 = 1; q1 = 2; q2 = 3; }
    else if (bc == 2) { q0 = 3; q1 = 4; q2 = 5; }
    else              { q0 = 4; q1 = 5; q2 = 6; }

    const float* xb = x + (size_t)b * (1792 * 28);
#pragma unroll
    for (int sb = 0; sb < 2; ++sb) {
        const int u0 = sb * 3;
        float4 v0[3], v1[3];
#pragma unroll
        for (int u = 0; u < 3; ++u) {
            int P = tid + ((u0 + u) << 9);
            if (P < 2688) {
                int rp = P / 3, q3 = P - rp * 3;
                int q  = (q3 == 0) ? q0 : ((q3 == 1) ? q1 : q2);
                int a  = rp % 28, jp = rp / 28;
                const float* p0 = xb + (jp * 56 + a) * 28 + (q << 2);
                v0[u] = *reinterpret_cast<const float4*>(p0);
                v1[u] = *reinterpret_cast<const float4*>(p0 + 784);
            }
        }
#pragma unroll
        for (int u = 0; u < 3; ++u) {
            int P = tid + ((u0 + u) << 9);
            if (P < 2688) {
                int rp = P / 3, q3 = P - rp * 3;
                int q  = (q3 == 0) ? q0 : ((q3 == 1) ? q1 : q2);
                int a  = rp % 28, jp = rp / 28;
                int a13 = a * 13;
                int j4  = jp << 2;
                float lo4[4] = {v0[u].x, v0[u].y, v0[u].z, v0[u].w};
                float hi4[4] = {v1[u].x, v1[u].y, v1[u].z, v1[u].w};
#pragma unroll
                for (int e = 0; e < 4; ++e) {
                    int n = (q << 2) + e;
                    int sl; bool ok;
                    if (bc == 0) {
                        if (n < 8)        { sl = n + 1;  ok = true; }
                        else if (n >= 26) { sl = n - 17; ok = true; }
                        else              { sl = 0;      ok = false; }
                    } else {
                        sl = n + 2 - c0;
                        ok = (unsigned)sl < 10u;
                    }
                    if (ok) {
                        int row  = a13 + sl;
                        int byte = (row << 7) + (j4 ^ ((row & 7) << 4));
                        unsigned int pk;
                        asm("v_cvt_pk_bf16_f32 %0, %1, %2" : "=v"(pk) : "v"(lo4[e]), "v"(hi4[e]));
                        *(unsigned int*)(smem + byte) = pk;
                    }
                }
            }
        }
    }
    __syncthreads();

    // ---- K-loop: per wave 7 m-tiles x 2 n-tiles, 6 K-steps of 32 ----
    const int cl  = rl & 7;
    const int rh  = rl >> 3;
    const int mt0 = (w >> 2) * 7;       // wave-half m-tile base
    const int wn  = w & 3;              // n-group
    int rowoff[3];
#pragma unroll
    for (int k = 0; k < 3; ++k) {
        int sIdx = (bc == 0) ? ((cl == 0) ? (9 + k) : (cl - 1 + k)) : (cl + k);
        rowoff[k] = rh * 13 + sIdx;
    }

    f32x4 acc[7][2];
#pragma unroll
    for (int mt = 0; mt < 7; ++mt) {
        acc[mt][0] = f32x4{0.f, 0.f, 0.f, 0.f};
        acc[mt][1] = f32x4{0.f, 0.f, 0.f, 0.f};
    }

#pragma unroll
    for (int s = 0; s < 6; ++s) {
        const int k  = s >> 1;
        const int jb = ((s & 1) << 5) + jb0;
        const int jx = jb << 1;
        bf16x8 b0 = *reinterpret_cast<const bf16x8*>(wt + (k << 13) + (((wn << 5) + rl) << 6) + jb);
        bf16x8 b1 = *reinterpret_cast<const bf16x8*>(wt + (k << 13) + (((wn << 5) + 16 + rl) << 6) + jb);
#pragma unroll
        for (int mt = 0; mt < 7; ++mt) {
            int row  = 26 * (mt0 + mt) + rowoff[k];
            int byte = (row << 7) + (jx ^ ((row & 7) << 4));
            bf16x8 af = *reinterpret_cast<const bf16x8*>(smem + byte);
            acc[mt][0] = __builtin_amdgcn_mfma_f32_16x16x32_bf16(af, b0, acc[mt][0], 0, 0, 0);
            acc[mt][1] = __builtin_amdgcn_mfma_f32_16x16x32_bf16(af, b1, acc[mt][1], 0, 0, 0);
        }
    }
    __syncthreads();

    // ---- epilogue: plain-C++ pack + 1 b64 write per (mt,p); t4s[ic][l][cl] ----
    {
        const int rq  = (lane >> 4) << 2;
        const int icb = (wn << 5) + rl;
#pragma unroll
        for (int mt = 0; mt < 7; ++mt) {
            int rbase = ((mt0 + mt) << 4) + rq;
            int a     = rbase >> 3;
            int l     = (a == 27) ? 0 : (a + 1);    // roll applied at write
            int clb   = rbase & 7;                  // 0 or 4
            int lofs  = (l << 4) + (clb << 1);
#pragma unroll
            for (int p = 0; p < 2; ++p) {
                int ic = icb + (p << 4);
                unsigned int pk0 = (unsigned int)f2b(acc[mt][p][0])
                                 | ((unsigned int)f2b(acc[mt][p][1]) << 16);
                unsigned int pk1 = (unsigned int)f2b(acc[mt][p][2])
                                 | ((unsigned int)f2b(acc[mt][p][3]) << 16);
                u32x2 pk; pk.x = pk0; pk.y = pk1;
                *reinterpret_cast<u32x2*>(smem + ic * 464 + lofs) = pk;
            }
        }
    }
    __syncthreads();

    // ---- combine: task (iloc, lq) reads 4 b128 rows, computes all 7 m ----
#pragma unroll
    for (int u = 0; u < 2; ++u) {
        int f = tid + (u << 9);
        if (f < 896) {
            int lq   = f % 7;
            int iloc = f / 7;                    // 0..127
            float w00 = w0s[2 * iloc], w01 = w0s[2 * iloc + 1];
            const char* base = smem + iloc * 464 + (lq << 6);
            u32x4 v_[4];
#pragma unroll
            for (int u4 = 0; u4 < 4; ++u4)
                v_[u4] = *reinterpret_cast<const u32x4*>(base + (u4 << 4));
            float* yb = y + (size_t)b * 100352 + (size_t)iloc * 784 + c0 * 28 + (lq << 2);
#pragma unroll
            for (int m = 0; m < 7; ++m) {
                f32x4 o;
#pragma unroll
                for (int u4 = 0; u4 < 4; ++u4) {
                    float cm, cm1;                       // cl=m_loc, cl=m_loc+1
                    if ((m & 1) == 0) {
                        unsigned int wd = v_[u4][m >> 1];
                        cm  = lo2f(wd);
                        cm1 = hi2f(wd);
                    } else {
                        cm  = hi2f(v_[u4][m >> 1]);
                        cm1 = lo2f(v_[u4][(m + 1) >> 1]);
                    }
                    o[u4] = w00 * cm1 + w01 * cm;
                }
                __builtin_nontemporal_store(
                    o, reinterpret_cast<f32x4*>(yb + m * 28));
            }
        }
    }
}

extern "C" void kernel_launch(void* const* d_in, const int* in_sizes, int n_in,
                              void* d_out, int out_size, void* d_ws, size_t ws_size,
                              hipStream_t stream) {
    const float* x  = (const float*)d_in[0];
    const float* w0 = (const float*)d_in[1];
    const float* w1 = (const float*)d_in[2];
    float* y = (float*)d_out;
    unsigned short* wt = (unsigned short*)d_ws;   // 24576 u16 = 48 KiB

    hipLaunchKernelGGL(wt_prepass, dim3(96), dim3(256), 0, stream, w1, wt);
    hipLaunchKernelGGL(fused_main, dim3(4096), dim3(512), 0, stream, x, w0, wt, y);
}

// Round 22
// 150.906 us; speedup vs baseline: 1.4533x; 1.4533x over previous
//
#include <hip/hip_runtime.h>

typedef short bf16x8 __attribute__((ext_vector_type(8)));
typedef float f32x4 __attribute__((ext_vector_type(4)));
typedef unsigned short u16x4 __attribute__((ext_vector_type(4)));

__device__ __forceinline__ unsigned short f2b(float f) {
    unsigned int u = __builtin_bit_cast(unsigned int, f);
    u += 0x7fffu + ((u >> 16) & 1u);   // RNE
    return (unsigned short)(u >> 16);
}
__device__ __forceinline__ float b2f(unsigned short s) {
    unsigned int u = ((unsigned int)s) << 16;
    return __builtin_bit_cast(float, u);
}

// wt[k][i][j] = bf16(w1[j][k][i]);  k<3, i<128, j<64
__global__ void wt_prepass(const float* __restrict__ w1, unsigned short* __restrict__ wt) {
    int t = blockIdx.x * 256 + threadIdx.x;
    if (t >= 24576) return;
    int j = t & 63;
    int i = (t >> 6) & 127;
    int k = t >> 13;
    wt[t] = f2b(w1[(j * 3 + k) * 128 + i]);
}

// xs: row = a*13 + s; byte = (row<<7) + ((j*2) ^ ((row&7)<<4))   [46592 B]
// t4s (overlay): [ic][cl][l] u16, byte = ic*512 + cl*64 + ((l*2) ^ (((ic*7+cl)&7)<<3))
// 512-thread block, one (b,bc) tile; staging writes j-PAIRS as b32 via v_cvt_pk_bf16_f32.
// single-batch staging: all 6 pair-loads (12 float4) in flight before the scatter.

__global__ __launch_bounds__(512, 4) void fused_main(
        const float* __restrict__ x, const float* __restrict__ w0,
        const unsigned short* __restrict__ wt, float* __restrict__ y) {
    __shared__ __align__(16) char smem[65536];   // xs (46.6K) then t4s (64K)
    __shared__ float w0s[256];

    const int tid  = threadIdx.x;
    const int lane = tid & 63;
    const int w    = tid >> 6;          // 0..7
    const int rl   = lane & 15;
    const int jb0  = (lane >> 4) << 3;

    // same-XCD sibling mapping (bc-siblings of one b are 8 dispatch-slots apart)
    const int B   = (int)blockIdx.x;
    const int b   = ((B & 7) << 7) + ((B >> 3) >> 2);
    const int bc  = (B >> 3) & 3;
    const int c0  = 7 * bc;

    if (tid < 256) w0s[tid] = w0[tid];

    // ---- zero-fill halo slots (bc0: s=0,11 ; bc3: s=9) ----
    {
        int nh = (bc == 0) ? 2 : ((bc == 3) ? 1 : 0);
        for (int idx = tid; idx < nh * 224; idx += 512) {
            int rr = idx;
            int sl;
            if (bc == 0) {
                if (rr >= 224) { sl = 11; rr -= 224; } else sl = 0;
            } else {
                sl = 9;                 // bc == 3
            }
            int a   = rr >> 3, ch = rr & 7;
            int row = a * 13 + sl;
            int byte = (row << 7) + ((ch << 4) ^ ((row & 7) << 4));
            *reinterpret_cast<f32x4*>(smem + byte) = f32x4{0.f, 0.f, 0.f, 0.f};
        }
    }

    // ---- staging: single batch of 6 pair-units (rows 2jp, 2jp+1), b32 packed scatter ----
    int q0, q1, q2;
    if      (bc == 0) { q0 = 0; q1 = 1; q2 = 6; }
    else if (bc == 1) { q0 = 1; q1 = 2; q2 = 3; }
    else if (bc == 2) { q0 = 3; q1 = 4; q2 = 5; }
    else              { q0 = 4; q1 = 5; q2 = 6; }

    const float* xb = x + (size_t)b * (1792 * 28);
    {
        float4 v0[6], v1[6];
#pragma unroll
        for (int u = 0; u < 6; ++u) {
            int P = tid + (u << 9);
            if (P < 2688) {
                int rp = P / 3, q3 = P - rp * 3;
                int q  = (q3 == 0) ? q0 : ((q3 == 1) ? q1 : q2);
                int a  = rp % 28, jp = rp / 28;
                const float* p0 = xb + (jp * 56 + a) * 28 + (q << 2);
                v0[u] = *reinterpret_cast<const float4*>(p0);
                v1[u] = *reinterpret_cast<const float4*>(p0 + 784);
            }
        }
#pragma unroll
        for (int u = 0; u < 6; ++u) {
            int P = tid + (u << 9);
            if (P < 2688) {
                int rp = P / 3, q3 = P - rp * 3;
                int q  = (q3 == 0) ? q0 : ((q3 == 1) ? q1 : q2);
                int a  = rp % 28, jp = rp / 28;
                int a13 = a * 13;
                int j4  = jp << 2;
                float lo4[4] = {v0[u].x, v0[u].y, v0[u].z, v0[u].w};
                float hi4[4] = {v1[u].x, v1[u].y, v1[u].z, v1[u].w};
#pragma unroll
                for (int e = 0; e < 4; ++e) {
                    int n = (q << 2) + e;
                    int sl; bool ok;
                    if (bc == 0) {
                        if (n < 8)        { sl = n + 1;  ok = true; }
                        else if (n >= 26) { sl = n - 17; ok = true; }
                        else              { sl = 0;      ok = false; }
                    } else {
                        sl = n + 2 - c0;
                        ok = (unsigned)sl < 10u;
                    }
                    if (ok) {
                        int row  = a13 + sl;
                        int byte = (row << 7) + (j4 ^ ((row & 7) << 4));
                        unsigned int pk;
                        asm("v_cvt_pk_bf16_f32 %0, %1, %2" : "=v"(pk) : "v"(lo4[e]), "v"(hi4[e]));
                        *(unsigned int*)(smem + byte) = pk;
                    }
                }
            }
        }
    }
    __syncthreads();

    // ---- K-loop: per wave 7 m-tiles x 2 n-tiles, 6 K-steps of 32 ----
    const int cl  = rl & 7;
    const int rh  = rl >> 3;
    const int mt0 = (w >> 2) * 7;       // wave-half m-tile base
    const int wn  = w & 3;              // n-group
    int rowoff[3];
#pragma unroll
    for (int k = 0; k < 3; ++k) {
        int sIdx = (bc == 0) ? ((cl == 0) ? (9 + k) : (cl - 1 + k)) : (cl + k);
        rowoff[k] = rh * 13 + sIdx;
    }

    f32x4 acc[7][2];
#pragma unroll
    for (int mt = 0; mt < 7; ++mt) {
        acc[mt][0] = f32x4{0.f, 0.f, 0.f, 0.f};
        acc[mt][1] = f32x4{0.f, 0.f, 0.f, 0.f};
    }

#pragma unroll
    for (int s = 0; s < 6; ++s) {
        const int k  = s >> 1;
        const int jb = ((s & 1) << 5) + jb0;
        const int jx = jb << 1;
        bf16x8 b0 = *reinterpret_cast<const bf16x8*>(wt + (k << 13) + (((wn << 5) + rl) << 6) + jb);
        bf16x8 b1 = *reinterpret_cast<const bf16x8*>(wt + (k << 13) + (((wn << 5) + 16 + rl) << 6) + jb);
#pragma unroll
        for (int mt = 0; mt < 7; ++mt) {
            int row  = 26 * (mt0 + mt) + rowoff[k];
            int byte = (row << 7) + (jx ^ ((row & 7) << 4));
            bf16x8 af = *reinterpret_cast<const bf16x8*>(smem + byte);
            acc[mt][0] = __builtin_amdgcn_mfma_f32_16x16x32_bf16(af, b0, acc[mt][0], 0, 0, 0);
            acc[mt][1] = __builtin_amdgcn_mfma_f32_16x16x32_bf16(af, b1, acc[mt][1], 0, 0, 0);
        }
    }
    __syncthreads();

    // ---- epilogue writes: t4s[ic][cl][l], scalar b16 ----
    {
        const int rq  = (lane >> 4) << 2;
        const int icb = (wn << 5) + rl;
#pragma unroll
        for (int mt = 0; mt < 7; ++mt) {
            int rbase = ((mt0 + mt) << 4) + rq;
            int a     = rbase >> 3;
            int l     = (a == 27) ? 0 : (a + 1);    // roll applied at write
            int l2    = l << 1;
            int clb   = rbase & 7;                  // 0 or 4
#pragma unroll
            for (int p = 0; p < 2; ++p) {
                int ic   = icb + (p << 4);
                int base = (ic << 9);
                int ic7  = ic * 7;
#pragma unroll
                for (int q = 0; q < 4; ++q) {
                    int cc   = clb + q;
                    int byte = base + (cc << 6) + (l2 ^ (((ic7 + cc) & 7) << 3));
                    *(unsigned short*)(smem + byte) = f2b(acc[mt][p][q]);
                }
            }
        }
    }
    __syncthreads();

    // ---- combine with w0: 2 x ds_read_b64 per output float4; nt stores ----
#pragma unroll
    for (int u = 0; u < 13; ++u) {
        int f = tid + (u << 9);
        if (f < 6272) {
            int lq    = f % 7;
            int t1    = f / 7;
            int m_loc = t1 % 7;
            int iloc  = t1 / 7;                     // 0..127
            float w00 = w0s[2 * iloc], w01 = w0s[2 * iloc + 1];
            int m     = c0 + m_loc;
            int lo    = lq << 3;
            int i7    = iloc * 7;
            int cl1   = m_loc + 1;                  // c = m
            int cl2   = m_loc;                      // c = m-1
            int by1   = (iloc << 9) + (cl1 << 6) + (lo ^ (((i7 + cl1) & 7) << 3));
            int by2   = (iloc << 9) + (cl2 << 6) + (lo ^ (((i7 + cl2) & 7) << 3));
            u16x4 h1  = *reinterpret_cast<const u16x4*>(smem + by1);
            u16x4 h2  = *reinterpret_cast<const u16x4*>(smem + by2);
            f32x4 o;
            o.x = w00 * b2f(h1.x) + w01 * b2f(h2.x);
            o.y = w00 * b2f(h1.y) + w01 * b2f(h2.y);
            o.z = w00 * b2f(h1.z) + w01 * b2f(h2.z);
            o.w = w00 * b2f(h1.w) + w01 * b2f(h2.w);
            __builtin_nontemporal_store(
                o, reinterpret_cast<f32x4*>(y + ((((size_t)b * 128 + iloc) * 28 + m) * 28) + (lq << 2)));
        }
    }
}

extern "C" void kernel_launch(void* const* d_in, const int* in_sizes, int n_in,
                              void* d_out, int out_size, void* d_ws, size_t ws_size,
                              hipStream_t stream) {
    const float* x  = (const float*)d_in[0];
    const float* w0 = (const float*)d_in[1];
    const float* w1 = (const float*)d_in[2];
    float* y = (float*)d_out;
    unsigned short* wt = (unsigned short*)d_ws;   // 24576 u16 = 48 KiB

    hipLaunchKernelGGL(wt_prepass, dim3(96), dim3(256), 0, stream, w1, wt);
    hipLaunchKernelGGL(fused_main, dim3(4096), dim3(512), 0, stream, x, w0, wt, y);
}